// Round 7
// baseline (209.307 us; speedup 1.0000x reference)
//
#include <hip/hip_runtime.h>
#include <hip/hip_bf16.h>

#define N_EMBD 1024
#define NW     110592
#define NCHUNK 96

typedef __attribute__((ext_vector_type(8)))  short          short8;
typedef __attribute__((ext_vector_type(8)))  unsigned short ushort8;
typedef __attribute__((ext_vector_type(16))) float          floatx16;
typedef __attribute__((ext_vector_type(4)))  float          float4v;
typedef __attribute__((ext_vector_type(2)))  float          float2v;

// chunk sizes: 48 x 1024, 24 x 2048, 24 x 512
__device__ __forceinline__ void chunk_info(int l, int& S, int& off) {
  if (l < 48)      { S = 1024; off = l * 1024; }
  else if (l < 72) { S = 2048; off = 49152 + (l - 48) * 2048; }
  else             { S = 512;  off = 98304 + (l - 72) * 512; }
}

// fp32 -> bf16 round-to-nearest-even
__device__ __forceinline__ unsigned short f2bf(float f) {
  unsigned u = __float_as_uint(f);
  u += 0x7fffu + ((u >> 16) & 1u);
  return (unsigned short)(u >> 16);
}
__device__ __forceinline__ float bf2f(unsigned short u) {
  return __uint_as_float(((unsigned)u) << 16);
}

#define GLOAD_LDS16(g, l) \
  __builtin_amdgcn_global_load_lds((const __attribute__((address_space(1))) unsigned int*)(g), \
                                   (__attribute__((address_space(3))) unsigned int*)(l), 16, 0, 0)

// ---------------- transpose: xswz[kb][b][e] = bf16(P[b][kb*8+e])
__global__ __launch_bounds__(256) void xpose_kernel(
    const float* __restrict__ P, unsigned short* __restrict__ xswz) {
  int t = blockIdx.x * 256 + threadIdx.x;   // t < (NW/8)*32
  int b = t & 31, kb = t >> 5;
  const float* src = P + (size_t)b * NW + (size_t)kb * 8;
  float4v v0 = *(const float4v*)(src);
  float4v v1 = *(const float4v*)(src + 4);
  ushort8 o;
#pragma unroll
  for (int j = 0; j < 4; ++j) { o[j] = f2bf(v0[j]); o[j + 4] = f2bf(v1[j]); }
  *(ushort8*)(xswz + (size_t)t * 8) = o;
}

// ---------------- encoder: reps[l,b,d] = sum_k x[b,off+k] * We[l][k][d]
// 384 blocks x 512 thr (8 waves), 32x256 tile, K-step 32, counted-vmcnt dbuf loop.
// NEW: writes reps directly in blocked dec-A layout AND emits per-block LN
// partial stats (sum,sumsq over its 256 cols) from f32 accumulators.
__global__ __launch_bounds__(512) void enc_kernel(
    const unsigned short* __restrict__ xswz, const float* __restrict__ We,
    unsigned short* __restrict__ repsB, float* __restrict__ blockStats) {
  __shared__ float Bt[2][32][256];
  __shared__ float part[8][32][2];
  int id = blockIdx.x;
  int x = id & 7, j = id >> 3;                 // j in 0..47 per XCD
  int l, ti;
  if (j < 12)      { l = 48 + x + 8 * (j >> 2); ti = j & 3; }                    // heavy  S=2048
  else if (j < 36) { int jm = j - 12; l = x + 8 * (jm >> 2); ti = jm & 3; }      // medium S=1024
  else             { int jl = j - 36; l = 72 + x + 8 * (jl >> 2); ti = jl & 3; } // light  S=512
  int S, off; chunk_info(l, S, off);

  int tid = threadIdx.x, w = tid >> 6, lane = tid & 63;
  int lo = lane & 31, hi = lane >> 5;
  int c0 = ti * 256;

  const float* Wb = We + (size_t)l * (2048 * N_EMBD) + c0 + (lane << 2);
  const unsigned short* Ab = xswz + (size_t)off * 32 + lo * 8;

#define STAGE(buf, k0) { _Pragma("unroll") \
    for (int q = 0; q < 4; ++q) \
      GLOAD_LDS16(Wb + (size_t)((k0) + w * 4 + q) * N_EMBD, &Bt[buf][w * 4 + q][0]); }
#define AFL(k0, ks) (*(const short8*)(Ab + (size_t)((k0) + (ks) * 16 + hi * 8) * 32))

  floatx16 acc = {};
  short8 aA0 = AFL(0, 0), aA1 = AFL(0, 1);
  STAGE(0, 0);
  asm volatile("" ::: "memory");

  int nt = S >> 5;
  for (int t = 0; t < nt; ++t) {
    int k0 = t << 5, cur = t & 1;
    short8 aB0, aB1;
    if (t + 1 < nt) {
      aB0 = AFL(k0 + 32, 0); aB1 = AFL(k0 + 32, 1);
      STAGE(cur ^ 1, k0 + 32);
      __builtin_amdgcn_sched_barrier(0);
      asm volatile("s_waitcnt vmcnt(6)" ::: "memory");
    } else {
      __builtin_amdgcn_sched_barrier(0);
      asm volatile("s_waitcnt vmcnt(0)" ::: "memory");
    }
    __builtin_amdgcn_s_barrier();
    __builtin_amdgcn_sched_barrier(0);
    short8 bf0, bf1;
#pragma unroll
    for (int jj = 0; jj < 8; ++jj) bf0[jj] = (short)f2bf(Bt[cur][hi * 8 + jj][w * 32 + lo]);
#pragma unroll
    for (int jj = 0; jj < 8; ++jj) bf1[jj] = (short)f2bf(Bt[cur][16 + hi * 8 + jj][w * 32 + lo]);
    acc = __builtin_amdgcn_mfma_f32_32x32x16_bf16(aA0, bf0, acc, 0, 0, 0);
    acc = __builtin_amdgcn_mfma_f32_32x32x16_bf16(aA1, bf1, acc, 0, 0, 0);
    __builtin_amdgcn_sched_barrier(0);
    __builtin_amdgcn_s_barrier();
    __builtin_amdgcn_sched_barrier(0);
    aA0 = aB0; aA1 = aB1;
  }
#undef STAGE
#undef AFL

  // ---- LN partial stats: butterfly over the 32 lo-lanes (fixed order, deterministic)
#pragma unroll
  for (int r = 0; r < 16; ++r) {
    float sv = acc[r], qv = acc[r] * acc[r];
#pragma unroll
    for (int m = 1; m < 32; m <<= 1) {
      sv += __shfl_xor(sv, m, 64);
      qv += __shfl_xor(qv, m, 64);
    }
    if (lo == 0) {
      int row = (r & 3) + 8 * (r >> 2) + 4 * hi;
      part[w][row][0] = sv;
      part[w][row][1] = qv;
    }
  }
  __syncthreads();
  if (tid < 64) {
    int row = tid >> 1, c = tid & 1;
    float tot = 0.f;
#pragma unroll
    for (int q = 0; q < 8; ++q) tot += part[q][row][c];
    blockStats[((l * 4 + ti) * 32 + row) * 2 + c] = tot;
  }

  // ---- write reps in blocked dec-A layout: addr = l*32768 + (d>>3)*256 + b*8 + (d&7)
  unsigned short* outp = repsB + (size_t)l * 32768
                       + (size_t)((c0 + w * 32) >> 3) * 256 + (lo >> 3) * 256 + (lo & 7);
#pragma unroll
  for (int r = 0; r < 16; ++r) {
    int row = (r & 3) + 8 * (r >> 2) + 4 * hi;   // batch index b
    outp[row * 8] = f2bf(acc[r]);
  }
}

// ---------------- decoder: out[b][off+j] = sum_d LN(reps)[l,b,d] * Wd[l][d][j]
// 432 blocks x 512 thr, 32x256 tiles, K=1024, counted-vmcnt loop (unchanged).
// NEW: LN applied in-register on A-fragments; mu/rs from blockStats (4 partials,
// fixed-order sum); gamma/beta preloaded to LDS as float2 (broadcast ds_read_b64).
__global__ __launch_bounds__(512) void dec_kernel(
    const unsigned short* __restrict__ repsB, const float* __restrict__ Wd,
    const float* __restrict__ gamma, const float* __restrict__ beta,
    const float* __restrict__ blockStats, float* __restrict__ out) {
  __shared__ float Bt[2][32][256];
  __shared__ float2 gbS[1024];
  int id = blockIdx.x;
  int x = id & 7, j = id >> 3;                 // j in 0..53 per XCD
  int l, ti;
  if (j < 24)      { l = 48 + x + 8 * (j >> 3); ti = j & 7; }                    // heavy  S=2048
  else if (j < 48) { int jm = j - 24; l = x + 8 * (jm >> 2); ti = jm & 3; }      // medium S=1024
  else             { int jl = j - 48; l = 72 + x + 8 * (jl >> 1); ti = jl & 1; } // light  S=512
  int S, off; chunk_info(l, S, off);

  int tid = threadIdx.x, w = tid >> 6, lane = tid & 63;
  int lo = lane & 31, hi = lane >> 5;
  int c0 = ti * 256;

  const float* Wb = Wd + (size_t)l * (N_EMBD * 2048) + c0 + (lane << 2);
  const unsigned short* Ab = repsB + (size_t)l * 32768 + lo * 8;

#define STAGE(buf, k0) { _Pragma("unroll") \
    for (int q = 0; q < 4; ++q) \
      GLOAD_LDS16(Wb + (size_t)((k0) + w * 4 + q) * 2048, &Bt[buf][w * 4 + q][0]); }
#define AFL(k0, ks) (*(const short8*)(Ab + (size_t)((k0) + (ks) * 16 + hi * 8) * 32))

  // LN stats for batch row = lo (fixed-order sum of the 4 enc-tile partials)
  float s = 0.f, q2 = 0.f;
#pragma unroll
  for (int t4 = 0; t4 < 4; ++t4) {
    s  += blockStats[((l * 4 + t4) * 32 + lo) * 2 + 0];
    q2 += blockStats[((l * 4 + t4) * 32 + lo) * 2 + 1];
  }
  float mu  = s * (1.f / 1024.f);
  float var = q2 * (1.f / 1024.f) - mu * mu;
  float rs  = rsqrtf(var + 1e-5f);
  float nmr = -mu * rs;

  // gamma/beta -> LDS float2 pairs
  {
    float2v gv = *(const float2v*)(gamma + tid * 2);
    float2v bv = *(const float2v*)(beta  + tid * 2);
    gbS[tid * 2]     = make_float2(gv[0], bv[0]);
    gbS[tid * 2 + 1] = make_float2(gv[1], bv[1]);
  }

  floatx16 acc = {};
  short8 aA0 = AFL(0, 0), aA1 = AFL(0, 1);
  STAGE(0, 0);
  // drain prologue (stats + gb + stage + A) so the loop's vmcnt(6) count is exact
  asm volatile("s_waitcnt vmcnt(0) lgkmcnt(0)" ::: "memory");
  __builtin_amdgcn_s_barrier();

  const int nt = N_EMBD >> 5;   // 32
  for (int t = 0; t < nt; ++t) {
    int k0 = t << 5, cur = t & 1;
    short8 aB0, aB1;
    if (t + 1 < nt) {
      aB0 = AFL(k0 + 32, 0); aB1 = AFL(k0 + 32, 1);
      STAGE(cur ^ 1, k0 + 32);
      __builtin_amdgcn_sched_barrier(0);
      asm volatile("s_waitcnt vmcnt(6)" ::: "memory");
    } else {
      __builtin_amdgcn_sched_barrier(0);
      asm volatile("s_waitcnt vmcnt(0)" ::: "memory");
    }
    __builtin_amdgcn_s_barrier();
    __builtin_amdgcn_sched_barrier(0);
    // apply LN affine to A-fragments in-register
    short8 af0, af1;
#pragma unroll
    for (int jj = 0; jj < 8; ++jj) {
      float2 gb0 = gbS[k0 + hi * 8 + jj];
      float v0 = bf2f((unsigned short)aA0[jj]);
      af0[jj] = (short)f2bf(fmaf(fmaf(v0, rs, nmr), gb0.x, gb0.y));
      float2 gb1 = gbS[k0 + 16 + hi * 8 + jj];
      float v1 = bf2f((unsigned short)aA1[jj]);
      af1[jj] = (short)f2bf(fmaf(fmaf(v1, rs, nmr), gb1.x, gb1.y));
    }
    short8 bf0, bf1;
#pragma unroll
    for (int jj = 0; jj < 8; ++jj) bf0[jj] = (short)f2bf(Bt[cur][hi * 8 + jj][w * 32 + lo]);
#pragma unroll
    for (int jj = 0; jj < 8; ++jj) bf1[jj] = (short)f2bf(Bt[cur][16 + hi * 8 + jj][w * 32 + lo]);
    acc = __builtin_amdgcn_mfma_f32_32x32x16_bf16(af0, bf0, acc, 0, 0, 0);
    acc = __builtin_amdgcn_mfma_f32_32x32x16_bf16(af1, bf1, acc, 0, 0, 0);
    __builtin_amdgcn_sched_barrier(0);
    __builtin_amdgcn_s_barrier();
    __builtin_amdgcn_sched_barrier(0);
    aA0 = aB0; aA1 = aB1;
  }
#undef STAGE
#undef AFL

#pragma unroll
  for (int r = 0; r < 16; ++r) {
    int row = (r & 3) + 8 * (r >> 2) + 4 * hi;  // batch index
    out[(size_t)row * NW + off + c0 + w * 32 + lo] = acc[r];
  }
}

extern "C" void kernel_launch(void* const* d_in, const int* in_sizes, int n_in,
                              void* d_out, int out_size, void* d_ws, size_t ws_size,
                              hipStream_t stream) {
  const float* P  = (const float*)d_in[0];
  const float* We = (const float*)d_in[1];
  const float* Wd = (const float*)d_in[2];
  const float* g  = (const float*)d_in[3];
  const float* bt = (const float*)d_in[4];
  float* out = (float*)d_out;

  unsigned short* xswz  = (unsigned short*)d_ws;                   // NW*32 bf16 = 7.08 MB
  unsigned short* repsB = xswz + (size_t)NW * 32;                  // 6.29 MB (blocked layout)
  float* blockStats = (float*)(repsB + (size_t)NCHUNK * 32 * N_EMBD);  // 96*4*32*2 f32 = 98 KB

  xpose_kernel<<<(NW / 8) * 32 / 256, 256, 0, stream>>>(P, xswz);
  enc_kernel<<<384, 512, 0, stream>>>(xswz, We, repsB, blockStats);
  dec_kernel<<<432, 512, 0, stream>>>(repsB, Wd, g, bt, blockStats, out);
}

// Round 8
// 208.127 us; speedup vs baseline: 1.0057x; 1.0057x over previous
//
#include <hip/hip_runtime.h>
#include <hip/hip_bf16.h>

#define N_EMBD 1024
#define NW     110592
#define NCHUNK 96

typedef __attribute__((ext_vector_type(8)))  short          short8;
typedef __attribute__((ext_vector_type(8)))  unsigned short ushort8;
typedef __attribute__((ext_vector_type(16))) float          floatx16;
typedef __attribute__((ext_vector_type(4)))  float          float4v;
typedef __attribute__((ext_vector_type(4)))  unsigned int   uint4v;

// chunk sizes: 48 x 1024, 24 x 2048, 24 x 512
__device__ __forceinline__ void chunk_info(int l, int& S, int& off) {
  if (l < 48)      { S = 1024; off = l * 1024; }
  else if (l < 72) { S = 2048; off = 49152 + (l - 48) * 2048; }
  else             { S = 512;  off = 98304 + (l - 72) * 512; }
}

// fp32 -> bf16 round-to-nearest-even
__device__ __forceinline__ unsigned short f2bf(float f) {
  unsigned u = __float_as_uint(f);
  u += 0x7fffu + ((u >> 16) & 1u);
  return (unsigned short)(u >> 16);
}
__device__ __forceinline__ float bf2f(unsigned short u) {
  return __uint_as_float(((unsigned)u) << 16);
}

// ---------------- transpose: xswz[kb][b][e] = bf16(P[b][kb*8+e])
__global__ __launch_bounds__(256) void xpose_kernel(
    const float* __restrict__ P, unsigned short* __restrict__ xswz) {
  int t = blockIdx.x * 256 + threadIdx.x;   // t < (NW/8)*32
  int b = t & 31, kb = t >> 5;
  const float* src = P + (size_t)b * NW + (size_t)kb * 8;
  float4v v0 = *(const float4v*)(src);
  float4v v1 = *(const float4v*)(src + 4);
  ushort8 o;
#pragma unroll
  for (int j = 0; j < 4; ++j) { o[j] = f2bf(v0[j]); o[j + 4] = f2bf(v1[j]); }
  *(ushort8*)(xswz + (size_t)t * 8) = o;
}

// =====================================================================
// Deep-pipeline GEMM body (shared by enc/dec), as macros.
// Tile: 32 rows(batch) x 256 cols, K-step 32. Quad-buffered bf16 pair-packed
// LDS B-tiles (Bt[4][16][256] u32 = 64 KB). Depth-3 prefetch, vmcnt(6) steady,
// ONE barrier per phase. Per tile per wave: 4 W-dwordx4 + 2 A-b128 = 6 VMEM.
// =====================================================================

// load W tile (t2) rows w*4..w*4+3, cols lane*4..+3 into float4v Wset[4], then A pair
#define LOADT(Wset, aset0, aset1, t2) {                                          \
    int kq_ = (t2) << 5;                                                         \
    _Pragma("unroll")                                                            \
    for (int q = 0; q < 4; ++q)                                                  \
      Wset[q] = *(const float4v*)(Wg + (size_t)(kq_ + w * 4 + q) * WROW);        \
    aset0 = *(const short8*)(Ab + (size_t)(kq_ + hi * 8) * 32);                  \
    aset1 = *(const short8*)(Ab + (size_t)(kq_ + 16 + hi * 8) * 32);             \
  }

// pack W regs (4 rows) into bf16 pairs and write 2 b128 to buffer bi
#define WRITET(bi, Wset) {                                                       \
    unsigned int pk[8];                                                          \
    _Pragma("unroll")                                                            \
    for (int c = 0; c < 4; ++c) {                                                \
      pk[c]     = (unsigned)f2bf(Wset[0][c]) | ((unsigned)f2bf(Wset[1][c]) << 16); \
      pk[c + 4] = (unsigned)f2bf(Wset[2][c]) | ((unsigned)f2bf(Wset[3][c]) << 16); \
    }                                                                            \
    uint4v v0_ = {pk[0], pk[1], pk[2], pk[3]};                                   \
    uint4v v1_ = {pk[4], pk[5], pk[6], pk[7]};                                   \
    *(uint4v*)&Bt[bi][w * 2 + 0][lane * 4] = v0_;                                \
    *(uint4v*)&Bt[bi][w * 2 + 1][lane * 4] = v1_;                                \
  }

// one pipeline phase at absolute tile t (compile-time reg rotation via caller)
#define PHASE(t, Wld, ald0, ald1, Wwr, ause0, ause1) {                           \
    if ((t) + 2 < nt) LOADT(Wld, ald0, ald1, (t) + 2);                           \
    int rem_ = nt - 1 - (t);                                                     \
    __builtin_amdgcn_sched_barrier(0);                                           \
    if (rem_ >= 2) asm volatile("s_waitcnt vmcnt(6)" ::: "memory");              \
    else           asm volatile("s_waitcnt vmcnt(0)" ::: "memory");              \
    __builtin_amdgcn_sched_barrier(0);                                           \
    if ((t) + 1 < nt) WRITET(((t) + 1) & 3, Wwr);                                \
    {                                                                            \
      const unsigned int* bp_ = &Bt[(t) & 3][hi * 4][wcol];                      \
      uint4v r0_ = {bp_[0], bp_[256], bp_[512], bp_[768]};                       \
      uint4v r1_ = {bp_[2048], bp_[2304], bp_[2560], bp_[2816]};                 \
      acc = __builtin_amdgcn_mfma_f32_32x32x16_bf16(                             \
          ause0, __builtin_bit_cast(short8, r0_), acc, 0, 0, 0);                 \
      acc = __builtin_amdgcn_mfma_f32_32x32x16_bf16(                             \
          ause1, __builtin_bit_cast(short8, r1_), acc, 0, 0, 0);                 \
    }                                                                            \
    asm volatile("s_waitcnt lgkmcnt(0)" ::: "memory");                           \
    __builtin_amdgcn_sched_barrier(0);                                           \
    __builtin_amdgcn_s_barrier();                                                \
    __builtin_amdgcn_sched_barrier(0);                                           \
  }

#define GEMM_PIPELINE() {                                                        \
    LOADT(Wa, a00, a01, 0);                                                      \
    LOADT(Wb, a10, a11, 1);                                                      \
    __builtin_amdgcn_sched_barrier(0);                                           \
    asm volatile("s_waitcnt vmcnt(6)" ::: "memory");                             \
    __builtin_amdgcn_sched_barrier(0);                                           \
    WRITET(0, Wa);                                                               \
    asm volatile("s_waitcnt lgkmcnt(0)" ::: "memory");                           \
    __builtin_amdgcn_sched_barrier(0);                                           \
    __builtin_amdgcn_s_barrier();                                                \
    __builtin_amdgcn_sched_barrier(0);                                           \
    for (int tb = 0; tb < nt; tb += 4) {                                         \
      PHASE(tb + 0, Wa, a20, a21, Wb, a00, a01);                                 \
      PHASE(tb + 1, Wb, a30, a31, Wa, a10, a11);                                 \
      PHASE(tb + 2, Wa, a00, a01, Wb, a20, a21);                                 \
      PHASE(tb + 3, Wb, a10, a11, Wa, a30, a31);                                 \
    }                                                                            \
  }

// ---------------- encoder: reps[l*32+b][d] = sum_k x[b,off+k] * We[l][k][d]
// 384 blocks x 512 thr; per-XCD heavy-first mapping (4 x 256-col tiles/chunk).
__global__ __launch_bounds__(512, 4) void enc_kernel(
    const unsigned short* __restrict__ xswz, const float* __restrict__ We,
    unsigned short* __restrict__ reps) {
  __shared__ unsigned int Bt[4][16][256];
  int id = blockIdx.x;
  int x = id & 7, j = id >> 3;                 // j in 0..47 per XCD
  int l, ti;
  if (j < 12)      { l = 48 + x + 8 * (j >> 2); ti = j & 3; }                    // heavy  S=2048
  else if (j < 36) { int jm = j - 12; l = x + 8 * (jm >> 2); ti = jm & 3; }      // medium S=1024
  else             { int jl = j - 36; l = 72 + x + 8 * (jl >> 2); ti = jl & 3; } // light  S=512
  int S, off; chunk_info(l, S, off);

  int tid = threadIdx.x, w = tid >> 6, lane = tid & 63;
  int lo = lane & 31, hi = lane >> 5;
  int c0 = ti * 256;
  int wcol = w * 32 + lo;
  const int WROW = N_EMBD;

  const float* Wg = We + (size_t)l * (2048 * N_EMBD) + c0 + lane * 4;
  const unsigned short* Ab = xswz + (size_t)off * 32 + lo * 8;

  floatx16 acc = {};
  short8 a00, a01, a10, a11, a20, a21, a30, a31;
  float4v Wa[4], Wb[4];
  int nt = S >> 5;

  GEMM_PIPELINE();

  // C/D: col = lane&31, row = (reg&3)+8*(reg>>2)+4*(lane>>5)
  unsigned short* outp = reps + (size_t)(l * 32) * N_EMBD + c0 + wcol;
#pragma unroll
  for (int r = 0; r < 16; ++r) {
    int row = (r & 3) + 8 * (r >> 2) + 4 * hi;
    outp[(size_t)row * N_EMBD] = f2bf(acc[r]);
  }
}

// ---------------- layernorm rows of reps -> rlnswz in blocked layout
// rlnswz elem addr = l*32768 + (d>>3)*256 + b*8 + (d&7). grid 768 x 256, wave/row.
__global__ __launch_bounds__(256) void ln_kernel(
    const unsigned short* __restrict__ reps, const float* __restrict__ gamma,
    const float* __restrict__ beta, unsigned short* __restrict__ rlnswz) {
  int row  = blockIdx.x * 4 + (threadIdx.x >> 6);
  int lane = threadIdx.x & 63;
  int l = row >> 5, b = row & 31;
  const unsigned short* rp = reps + (size_t)row * N_EMBD;

  float x[16];
#pragma unroll
  for (int j = 0; j < 2; ++j) {
    int g = j * 64 + lane;
    ushort8 v = *(const ushort8*)(rp + g * 8);
#pragma unroll
    for (int t = 0; t < 8; ++t) x[j * 8 + t] = bf2f(v[t]);
  }
  float s = 0.f, s2 = 0.f;
#pragma unroll
  for (int i = 0; i < 16; ++i) { s += x[i]; s2 += x[i] * x[i]; }
#pragma unroll
  for (int m = 1; m < 64; m <<= 1) {
    s  += __shfl_xor(s,  m, 64);
    s2 += __shfl_xor(s2, m, 64);
  }
  float mu  = s * (1.f / 1024.f);
  float var = s2 * (1.f / 1024.f) - mu * mu;
  float rs  = rsqrtf(var + 1e-5f);

  unsigned short* op = rlnswz + (size_t)l * 32768 + b * 8;
#pragma unroll
  for (int j = 0; j < 2; ++j) {
    int g = j * 64 + lane;
    float4v g0 = *(const float4v*)(gamma + g * 8);
    float4v g1 = *(const float4v*)(gamma + g * 8 + 4);
    float4v b0 = *(const float4v*)(beta + g * 8);
    float4v b1 = *(const float4v*)(beta + g * 8 + 4);
    ushort8 o;
#pragma unroll
    for (int t = 0; t < 4; ++t) {
      o[t]     = f2bf((x[j * 8 + t]     - mu) * rs * g0[t] + b0[t]);
      o[t + 4] = f2bf((x[j * 8 + 4 + t] - mu) * rs * g1[t] + b1[t]);
    }
    *(ushort8*)(op + (size_t)g * 256) = o;
  }
}

// ---------------- decoder: out[b][off+j] = sum_d rln[l*32+b][d] * Wd[l][d][j]
// 432 blocks x 512 thr, 32x256 tiles, K = 1024 (nt = 32).
__global__ __launch_bounds__(512, 4) void dec_kernel(
    const unsigned short* __restrict__ rlnswz, const float* __restrict__ Wd,
    float* __restrict__ out) {
  __shared__ unsigned int Bt[4][16][256];
  int id = blockIdx.x;
  int x = id & 7, j = id >> 3;                 // j in 0..53 per XCD
  int l, ti;
  if (j < 24)      { l = 48 + x + 8 * (j >> 3); ti = j & 7; }                    // heavy  S=2048
  else if (j < 48) { int jm = j - 24; l = x + 8 * (jm >> 2); ti = jm & 3; }      // medium S=1024
  else             { int jl = j - 48; l = 72 + x + 8 * (jl >> 1); ti = jl & 1; } // light  S=512
  int S, off; chunk_info(l, S, off);

  int tid = threadIdx.x, w = tid >> 6, lane = tid & 63;
  int lo = lane & 31, hi = lane >> 5;
  int c0 = ti * 256;
  int wcol = w * 32 + lo;
  const int WROW = 2048;

  const float* Wg = Wd + (size_t)l * (N_EMBD * 2048) + c0 + lane * 4;
  const unsigned short* Ab = rlnswz + (size_t)l * 32768 + lo * 8;

  floatx16 acc = {};
  short8 a00, a01, a10, a11, a20, a21, a30, a31;
  float4v Wa[4], Wb[4];
  const int nt = N_EMBD >> 5;   // 32

  GEMM_PIPELINE();

#pragma unroll
  for (int r = 0; r < 16; ++r) {
    int row = (r & 3) + 8 * (r >> 2) + 4 * hi;  // batch index
    out[(size_t)row * NW + off + c0 + wcol] = acc[r];
  }
}

extern "C" void kernel_launch(void* const* d_in, const int* in_sizes, int n_in,
                              void* d_out, int out_size, void* d_ws, size_t ws_size,
                              hipStream_t stream) {
  const float* P  = (const float*)d_in[0];
  const float* We = (const float*)d_in[1];
  const float* Wd = (const float*)d_in[2];
  const float* g  = (const float*)d_in[3];
  const float* bt = (const float*)d_in[4];
  float* out = (float*)d_out;

  unsigned short* xswz   = (unsigned short*)d_ws;                    // NW*32 bf16 = 7.08 MB
  unsigned short* reps   = xswz + (size_t)NW * 32;                   // 6.29 MB
  unsigned short* rlnswz = reps + (size_t)NCHUNK * 32 * N_EMBD;      // 6.29 MB

  xpose_kernel<<<(NW / 8) * 32 / 256, 256, 0, stream>>>(P, xswz);
  enc_kernel<<<384, 512, 0, stream>>>(xswz, We, reps);
  ln_kernel<<<768, 256, 0, stream>>>(reps, g, bt, rlnswz);
  dec_kernel<<<432, 512, 0, stream>>>(rlnswz, Wd, out);
}